// Round 1
// baseline (144.741 us; speedup 1.0000x reference)
//
#include <hip/hip_runtime.h>

// Problem constants (match reference)
constexpr int TT   = 8192;   // nb_territories
constexpr int HH   = 4096;   // hidden size
constexpr int NACT = 65536;  // action pairs

// ---------------------------------------------------------------------------
// K1: x = tanh(W_in @ p + b_in), W_in is [HH][TT] row-major.
// One 256-thread block per row; float4 coalesced loads; wave+LDS reduce.
// ---------------------------------------------------------------------------
__global__ __launch_bounds__(256) void k_gemv_in(
    const float* __restrict__ W, const float* __restrict__ p,
    const float* __restrict__ b, float* __restrict__ x)
{
    const int row = blockIdx.x;
    const int t   = threadIdx.x;
    const float4* __restrict__ Wr = reinterpret_cast<const float4*>(W + (size_t)row * TT);
    const float4* __restrict__ pv = reinterpret_cast<const float4*>(p);
    float acc = 0.f;
#pragma unroll
    for (int i = 0; i < TT / 4 / 256; ++i) {   // 8 iters
        float4 w = Wr[i * 256 + t];
        float4 q = pv[i * 256 + t];
        acc += w.x * q.x + w.y * q.y + w.z * q.z + w.w * q.w;
    }
#pragma unroll
    for (int off = 32; off; off >>= 1) acc += __shfl_down(acc, off, 64);
    __shared__ float s[4];
    if ((t & 63) == 0) s[t >> 6] = acc;
    __syncthreads();
    if (t == 0) x[row] = tanhf(s[0] + s[1] + s[2] + s[3] + b[row]);
}

// ---------------------------------------------------------------------------
// K2: torig = tanh(W_orig @ x + b_orig), tdest = tanh(W_dest @ x + b_dest).
// Grid = 2*TT blocks; block < TT -> orig row, else dest row. th = [torig|tdest].
// ---------------------------------------------------------------------------
__global__ __launch_bounds__(256) void k_gemv_heads(
    const float* __restrict__ Wo, const float* __restrict__ bo,
    const float* __restrict__ Wd, const float* __restrict__ bd,
    const float* __restrict__ x, float* __restrict__ th)
{
    const int bid = blockIdx.x;
    const int t   = threadIdx.x;
    const float* W; const float* b; int r;
    if (bid < TT) { W = Wo; b = bo; r = bid; }
    else          { W = Wd; b = bd; r = bid - TT; }
    const float4* __restrict__ Wr = reinterpret_cast<const float4*>(W + (size_t)r * HH);
    const float4* __restrict__ xv = reinterpret_cast<const float4*>(x);
    float acc = 0.f;
#pragma unroll
    for (int i = 0; i < HH / 4 / 256; ++i) {   // 4 iters
        float4 w = Wr[i * 256 + t];
        float4 q = xv[i * 256 + t];
        acc += w.x * q.x + w.y * q.y + w.z * q.z + w.w * q.w;
    }
#pragma unroll
    for (int off = 32; off; off >>= 1) acc += __shfl_down(acc, off, 64);
    __shared__ float s[4];
    if ((t & 63) == 0) s[t >> 6] = acc;
    __syncthreads();
    if (t == 0) th[bid] = tanhf(s[0] + s[1] + s[2] + s[3] + b[r]);
}

// ---------------------------------------------------------------------------
// K3: for each action (o,d): u = exp(torig[o]*tdest[d] - 1).
// Claim the (zeroed) output slot with atomicExch; only the unique claimant
// contributes u to the block partial sum (duplicates write identical u, so
// the stored value is correct regardless of winner).
// ---------------------------------------------------------------------------
__global__ __launch_bounds__(256) void k_scatter(
    const int* __restrict__ pa, const float* __restrict__ th,
    float* __restrict__ out, float* __restrict__ partial)
{
    const int i = blockIdx.x * 256 + threadIdx.x;
    const int o = pa[2 * i];
    const int d = pa[2 * i + 1];
    const float v = th[o] * th[TT + d];
    const float u = expf(v - 1.0f);            // shift-invariant: use m'=1.0
    float old = atomicExch(out + ((size_t)o * TT + d), u);
    float c = (old == 0.0f) ? u : 0.0f;        // count unique positions once
#pragma unroll
    for (int off = 32; off; off >>= 1) c += __shfl_down(c, off, 64);
    __shared__ float s[4];
    if ((threadIdx.x & 63) == 0) s[threadIdx.x >> 6] = c;
    __syncthreads();
    if (threadIdx.x == 0) partial[blockIdx.x] = s[0] + s[1] + s[2] + s[3];
}

// ---------------------------------------------------------------------------
// K4: every block deterministically reduces the 256 partials -> Z, then
// writes out[o*TT+d] = exp(v-1)/Z (idempotent for duplicate actions).
// ---------------------------------------------------------------------------
__global__ __launch_bounds__(256) void k_finalize(
    const int* __restrict__ pa, const float* __restrict__ th,
    const float* __restrict__ partial, float* __restrict__ out)
{
    float ps = partial[threadIdx.x];
#pragma unroll
    for (int off = 32; off; off >>= 1) ps += __shfl_down(ps, off, 64);
    __shared__ float s[4];
    __shared__ float invZ;
    if ((threadIdx.x & 63) == 0) s[threadIdx.x >> 6] = ps;
    __syncthreads();
    if (threadIdx.x == 0) invZ = 1.0f / (s[0] + s[1] + s[2] + s[3]);
    __syncthreads();
    const int i = blockIdx.x * 256 + threadIdx.x;
    const int o = pa[2 * i];
    const int d = pa[2 * i + 1];
    const float v = th[o] * th[TT + d];
    out[(size_t)o * TT + d] = expf(v - 1.0f) * invZ;
}

// ---------------------------------------------------------------------------
extern "C" void kernel_launch(void* const* d_in, const int* in_sizes, int n_in,
                              void* d_out, int out_size, void* d_ws, size_t ws_size,
                              hipStream_t stream)
{
    const int*   pa  = (const int*)  d_in[0];  // possible_actions [NACT,2] int32
    const float* p   = (const float*)d_in[1];  // presence [TT]
    const float* Win = (const float*)d_in[2];  // [HH,TT]
    const float* bin = (const float*)d_in[3];  // [HH]
    const float* Wo  = (const float*)d_in[4];  // [TT,HH]
    const float* bo  = (const float*)d_in[5];  // [TT]
    const float* Wd  = (const float*)d_in[6];  // [TT,HH]
    const float* bd  = (const float*)d_in[7];  // [TT]
    float* out = (float*)d_out;

    float* x       = (float*)d_ws;        // [HH]
    float* th      = x + HH;              // [2*TT]  (torig | tdest)
    float* partial = th + 2 * TT;         // [256]

    // All non-action outputs are exactly 0 (exp(-1000 - m) underflows in fp32).
    hipMemsetAsync(out, 0, (size_t)out_size * sizeof(float), stream);

    k_gemv_in   <<<HH,        256, 0, stream>>>(Win, p, bin, x);
    k_gemv_heads<<<2 * TT,    256, 0, stream>>>(Wo, bo, Wd, bd, x, th);
    k_scatter   <<<NACT / 256, 256, 0, stream>>>(pa, th, out, partial);
    k_finalize  <<<NACT / 256, 256, 0, stream>>>(pa, th, partial, out);
}